// Round 1
// baseline (3659.410 us; speedup 1.0000x reference)
//
#include <hip/hip_runtime.h>
#include <hip/hip_bf16.h>

#define NWAY 2
#define KSHOT 10
#define NSUP 20
#define VEC 352
#define HID 352
#define GATES 1408
#define LIN 300
#define L1C 298   // conv1 out length
#define P1 59     // pool1 out length
#define L2C 57    // conv2 out length
#define P2 11     // pool2 out length

__device__ __forceinline__ float sigf(float x) { return 1.0f / (1.0f + __expf(-x)); }

// ---------------- conv1 stats (pass over conv output, per-channel sum/sumsq) ----------------
__global__ __launch_bounds__(256) void conv1_stats(const float* __restrict__ x,
    const float* __restrict__ w, const float* __restrict__ bias,
    float* __restrict__ part, int N)
{
    __shared__ float xrow[LIN];
    __shared__ float ws[160], bs[32];
    __shared__ float redS[256], redQ[256];
    int t = threadIdx.x;
    if (t < 160) ws[t] = w[t];
    if (t < 32) bs[t] = bias[t];
    int c = t & 31, g = t >> 5;
    float sum = 0.f, sq = 0.f;
    for (int n = blockIdx.x; n < N; n += gridDim.x) {
        __syncthreads();
        for (int i = t; i < LIN; i += 256) xrow[i] = x[(size_t)n * LIN + i];
        __syncthreads();
        for (int l = g; l < L1C; l += 8) {
            float y = bs[c];
#pragma unroll
            for (int k = 0; k < 5; ++k) {
                int idx = l + k - 1;
                if (idx >= 0 && idx < LIN) y += ws[c * 5 + k] * xrow[idx];
            }
            sum += y; sq += y * y;
        }
    }
    redS[t] = sum; redQ[t] = sq;
    __syncthreads();
    if (g == 0) {
        float s = 0.f, q = 0.f;
        for (int gg = 0; gg < 8; ++gg) { s += redS[gg * 32 + c]; q += redQ[gg * 32 + c]; }
        part[blockIdx.x * 64 + c] = s;
        part[blockIdx.x * 64 + 32 + c] = q;
    }
}

__global__ void finalize_stats(const float* __restrict__ part, float* __restrict__ outMean,
    float* __restrict__ outIstd, double count, int nblocks)
{
    int c = threadIdx.x;
    if (c >= 32) return;
    double s = 0.0, q = 0.0;
    for (int b = 0; b < nblocks; ++b) { s += (double)part[b * 64 + c]; q += (double)part[b * 64 + 32 + c]; }
    double m = s / count;
    double v = q / count - m * m;
    outMean[c] = (float)m;
    outIstd[c] = (float)(1.0 / sqrt(v + 1e-5));
}

// ---------------- conv1 + BN + relu + maxpool5 -> h1 (N,32,59) ----------------
__global__ __launch_bounds__(256) void conv1_apply(const float* __restrict__ x,
    const float* __restrict__ w, const float* __restrict__ bias,
    const float* __restrict__ gam, const float* __restrict__ bet,
    const float* __restrict__ mean, const float* __restrict__ istd,
    float* __restrict__ h1, int N)
{
    __shared__ float xrow[LIN];
    __shared__ float ws[160], bs[32], scale[32], shift[32];
    int t = threadIdx.x;
    if (t < 160) ws[t] = w[t];
    if (t < 32) {
        bs[t] = bias[t];
        float sc = istd[t] * gam[t];
        scale[t] = sc;
        shift[t] = bet[t] - mean[t] * sc;
    }
    int n = blockIdx.x;
    for (int i = t; i < LIN; i += 256) xrow[i] = x[(size_t)n * LIN + i];
    __syncthreads();
    int c = t & 31, g = t >> 5;
    for (int lo = g; lo < P1; lo += 8) {
        float m = -1e30f;
#pragma unroll
        for (int dl = 0; dl < 5; ++dl) {
            int l = lo * 5 + dl;
            float y = bs[c];
#pragma unroll
            for (int k = 0; k < 5; ++k) {
                int idx = l + k - 1;
                if (idx >= 0 && idx < LIN) y += ws[c * 5 + k] * xrow[idx];
            }
            float v = fmaxf(y * scale[c] + shift[c], 0.f);
            m = fmaxf(m, v);
        }
        h1[((size_t)n * 32 + c) * P1 + lo] = m;
    }
}

// ---------------- conv2 stats ----------------
__global__ __launch_bounds__(256) void conv2_stats(const float* __restrict__ h1,
    const float* __restrict__ w2, const float* __restrict__ b2,
    float* __restrict__ part, int N)
{
    __shared__ float w2s[5120];       // layout [(ci*5+k)*32 + c]
    __shared__ float tile[32 * 60];
    __shared__ float b2s[32];
    __shared__ float redS[256], redQ[256];
    int t = threadIdx.x;
    for (int i = t; i < 5120; i += 256) w2s[i] = w2[(size_t)(i & 31) * 160 + (i >> 5)];
    if (t < 32) b2s[t] = b2[t];
    int c = t & 31, g = t >> 5;
    float sum = 0.f, sq = 0.f;
    for (int n = blockIdx.x; n < N; n += gridDim.x) {
        __syncthreads();
        for (int i = t; i < 32 * P1; i += 256) tile[(i / P1) * 60 + (i % P1)] = h1[(size_t)n * (32 * P1) + i];
        __syncthreads();
        for (int l = g; l < L2C; l += 8) {
            float y = b2s[c];
            for (int ci = 0; ci < 32; ++ci) {
                const float* tr = &tile[ci * 60];
#pragma unroll
                for (int k = 0; k < 5; ++k) {
                    int idx = l + k - 1;
                    if (idx >= 0 && idx < P1) y += w2s[(ci * 5 + k) * 32 + c] * tr[idx];
                }
            }
            sum += y; sq += y * y;
        }
    }
    redS[t] = sum; redQ[t] = sq;
    __syncthreads();
    if (g == 0) {
        float s = 0.f, q = 0.f;
        for (int gg = 0; gg < 8; ++gg) { s += redS[gg * 32 + c]; q += redQ[gg * 32 + c]; }
        part[blockIdx.x * 64 + c] = s;
        part[blockIdx.x * 64 + 32 + c] = q;
    }
}

// ---------------- conv2 + BN + relu + maxpool5 -> z (N,352) ----------------
__global__ __launch_bounds__(256) void conv2_apply(const float* __restrict__ h1,
    const float* __restrict__ w2, const float* __restrict__ b2,
    const float* __restrict__ gam, const float* __restrict__ bet,
    const float* __restrict__ mean, const float* __restrict__ istd,
    float* __restrict__ z, int N)
{
    __shared__ float w2s[5120];
    __shared__ float tile[32 * 60];
    __shared__ float b2s[32], scale[32], shift[32];
    int t = threadIdx.x;
    for (int i = t; i < 5120; i += 256) w2s[i] = w2[(size_t)(i & 31) * 160 + (i >> 5)];
    if (t < 32) {
        b2s[t] = b2[t];
        float sc = istd[t] * gam[t];
        scale[t] = sc;
        shift[t] = bet[t] - mean[t] * sc;
    }
    int n = blockIdx.x;
    for (int i = t; i < 32 * P1; i += 256) tile[(i / P1) * 60 + (i % P1)] = h1[(size_t)n * (32 * P1) + i];
    __syncthreads();
    int c = t >> 3, sub = t & 7;
    for (int lo = sub; lo < P2; lo += 8) {
        float m = -1e30f;
#pragma unroll
        for (int dl = 0; dl < 5; ++dl) {
            int l = lo * 5 + dl;
            float y = b2s[c];
            for (int ci = 0; ci < 32; ++ci) {
                const float* tr = &tile[ci * 60];
#pragma unroll
                for (int k = 0; k < 5; ++k) {
                    int idx = l + k - 1;
                    if (idx >= 0 && idx < P1) y += w2s[(ci * 5 + k) * 32 + c] * tr[idx];
                }
            }
            float v = fmaxf(y * scale[c] + shift[c], 0.f);
            m = fmaxf(m, v);
        }
        z[(size_t)n * VEC + c * P2 + lo] = m;
    }
}

// ---------------- support means + tiny LSTM steps + constant-vector precompute ----------------
// misc layout (floats): [0:32) mean1 [32:64) istd1 [64:96) mean2 [96:128) istd2
// [128:480) h1_f  [480:832) h2_f  [832:1184) c2_f
// [1184:2592) gf_const  [2592:4000) br_sum  [4000:5408) pre_s1  [5408:6816) pre_s0
__global__ __launch_bounds__(256) void small_precompute(
    const float* __restrict__ z,
    const float* __restrict__ wihf, const float* __restrict__ whhf,
    const float* __restrict__ bihf, const float* __restrict__ bhhf,
    const float* __restrict__ wihr, const float* __restrict__ bihr, const float* __restrict__ bhhr,
    float* __restrict__ misc)
{
    __shared__ float sup0[VEC], sup1[VEC], hbuf[HID], cbuf[HID], gbuf[GATES];
    int t = threadIdx.x;
    for (int v = t; v < VEC; v += 256) {
        float s0 = 0.f, s1 = 0.f;
        for (int k = 0; k < KSHOT; ++k) {
            s0 += z[(size_t)k * VEC + v];
            s1 += z[(size_t)(KSHOT + k) * VEC + v];
        }
        sup0[v] = s0 * 0.1f; sup1[v] = s1 * 0.1f;
    }
    __syncthreads();
    // forward step 0 (input sup0, state 0)
    for (int j = t; j < GATES; j += 256) {
        float a = bihf[j] + bhhf[j];
        const float* wr = &wihf[(size_t)j * VEC];
        for (int k = 0; k < VEC; ++k) a += wr[k] * sup0[k];
        gbuf[j] = a;
    }
    __syncthreads();
    for (int h = t; h < HID; h += 256) {
        float iv = sigf(gbuf[h]), gv = tanhf(gbuf[2 * HID + h]), ov = sigf(gbuf[3 * HID + h]);
        float cc = iv * gv;
        float hh = ov * tanhf(cc);
        cbuf[h] = cc; hbuf[h] = hh;
        misc[128 + h] = hh;                       // h1_f
    }
    __syncthreads();
    // forward step 1 (input sup1)
    for (int j = t; j < GATES; j += 256) {
        float a = bihf[j] + bhhf[j];
        const float* wr = &wihf[(size_t)j * VEC];
        const float* wh = &whhf[(size_t)j * VEC];
        for (int k = 0; k < VEC; ++k) a += wr[k] * sup1[k] + wh[k] * hbuf[k];
        gbuf[j] = a;
    }
    __syncthreads();
    for (int h = t; h < HID; h += 256) {
        float iv = sigf(gbuf[h]), fv = sigf(gbuf[HID + h]);
        float gv = tanhf(gbuf[2 * HID + h]), ov = sigf(gbuf[3 * HID + h]);
        float cc = fv * cbuf[h] + iv * gv;
        float hh = ov * tanhf(cc);
        misc[480 + h] = hh;                       // h2_f
        misc[832 + h] = cc;                       // c2_f
    }
    __syncthreads();
    for (int h = t; h < HID; h += 256) hbuf[h] = misc[480 + h];   // h2_f into LDS
    __syncthreads();
    for (int j = t; j < GATES; j += 256) {
        float bb = bihf[j] + bhhf[j];
        const float* wh = &whhf[(size_t)j * VEC];
        float a = bb;
        for (int k = 0; k < VEC; ++k) a += wh[k] * hbuf[k];
        misc[1184 + j] = a;                       // gf_const = h2_f@Whh_f^T + b
        float br = bihr[j] + bhhr[j];
        misc[2592 + j] = br;                      // br_sum
        const float* wr = &wihr[(size_t)j * VEC];
        float a1 = br, a0 = br;
        for (int k = 0; k < VEC; ++k) { a1 += wr[k] * sup1[k]; a0 += wr[k] * sup0[k]; }
        misc[4000 + j] = a1;                      // pre_s1
        misc[5408 + j] = a0;                      // pre_s0
    }
}

// ---------------- GEMM (Q x 352) @ (352 x 1408-rows-of-W) with fused LSTM cell ----------------
// cmode: 0 -> c_prev = 0 ; 1 -> c_prev = cprev[h] (const 352-vec) ; 2 -> c_prev = cprev[q*352+h]
__global__ __launch_bounds__(256) void lstm_gemm_cell(
    const float* __restrict__ X, const float* __restrict__ W,
    const float* __restrict__ biasv, const float* __restrict__ cprev,
    int cmode, float* __restrict__ h_out, float* __restrict__ c_out, int Q)
{
    __shared__ float Xs[32][132];
    __shared__ float Ws[32][68];
    int t = threadIdx.x;
    int tq = t & 15, th = t >> 4;
    int qblk = blockIdx.x * 128;
    int h0 = blockIdx.y * 16;
    int h = h0 + th;

    float acc[8][4];
#pragma unroll
    for (int j = 0; j < 8; ++j)
#pragma unroll
        for (int gi = 0; gi < 4; ++gi) acc[j][gi] = 0.f;

    int ql = t >> 1, kh = (t & 1) * 16;
    int qg = qblk + ql;
    int r = t >> 2, kq = (t & 3) * 8;
    int grow = (r & 3) * HID + h0 + (r >> 2);
    const float* xbase = X + (size_t)qg * VEC + kh;
    const float* wbase = W + (size_t)grow * VEC + kq;

    for (int k0 = 0; k0 < VEC; k0 += 32) {
        float4 xv0 = {0,0,0,0}, xv1 = {0,0,0,0}, xv2 = {0,0,0,0}, xv3 = {0,0,0,0};
        if (qg < Q) {
            xv0 = *(const float4*)(xbase + k0);
            xv1 = *(const float4*)(xbase + k0 + 4);
            xv2 = *(const float4*)(xbase + k0 + 8);
            xv3 = *(const float4*)(xbase + k0 + 12);
        }
        float4 wv0 = *(const float4*)(wbase + k0);
        float4 wv1 = *(const float4*)(wbase + k0 + 4);
        __syncthreads();
        Xs[kh + 0][ql] = xv0.x; Xs[kh + 1][ql] = xv0.y; Xs[kh + 2][ql] = xv0.z; Xs[kh + 3][ql] = xv0.w;
        Xs[kh + 4][ql] = xv1.x; Xs[kh + 5][ql] = xv1.y; Xs[kh + 6][ql] = xv1.z; Xs[kh + 7][ql] = xv1.w;
        Xs[kh + 8][ql] = xv2.x; Xs[kh + 9][ql] = xv2.y; Xs[kh +10][ql] = xv2.z; Xs[kh +11][ql] = xv2.w;
        Xs[kh +12][ql] = xv3.x; Xs[kh +13][ql] = xv3.y; Xs[kh +14][ql] = xv3.z; Xs[kh +15][ql] = xv3.w;
        Ws[kq + 0][r] = wv0.x; Ws[kq + 1][r] = wv0.y; Ws[kq + 2][r] = wv0.z; Ws[kq + 3][r] = wv0.w;
        Ws[kq + 4][r] = wv1.x; Ws[kq + 5][r] = wv1.y; Ws[kq + 6][r] = wv1.z; Ws[kq + 7][r] = wv1.w;
        __syncthreads();
#pragma unroll 4
        for (int kk = 0; kk < 32; ++kk) {
            float4 xa = *(const float4*)&Xs[kk][tq * 8];
            float4 xb = *(const float4*)&Xs[kk][tq * 8 + 4];
            float4 wv = *(const float4*)&Ws[kk][th * 4];
            float xq[8] = { xa.x, xa.y, xa.z, xa.w, xb.x, xb.y, xb.z, xb.w };
            float wg[4] = { wv.x, wv.y, wv.z, wv.w };
#pragma unroll
            for (int j = 0; j < 8; ++j)
#pragma unroll
                for (int gi = 0; gi < 4; ++gi)
                    acc[j][gi] = fmaf(xq[j], wg[gi], acc[j][gi]);
        }
    }

    float bi = biasv[h], bf = biasv[HID + h], bg = biasv[2 * HID + h], bo = biasv[3 * HID + h];
    float cc1 = (cmode == 1) ? cprev[h] : 0.f;
#pragma unroll
    for (int j = 0; j < 8; ++j) {
        int q = qblk + tq * 8 + j;
        if (q >= Q) break;
        float iv = sigf(acc[j][0] + bi);
        float fv = sigf(acc[j][1] + bf);
        float gv = tanhf(acc[j][2] + bg);
        float ov = sigf(acc[j][3] + bo);
        float cp = (cmode == 2) ? cprev[(size_t)q * HID + h] : cc1;
        float cnew = fv * cp + iv * gv;
        float hnew = ov * tanhf(cnew);
        h_out[(size_t)q * HID + h] = hnew;
        if (c_out) c_out[(size_t)q * HID + h] = cnew;
    }
}

// ---------------- cosine sims + softmax; one wave per query ----------------
__global__ __launch_bounds__(256) void final_sims(
    const float* __restrict__ h3f, const float* __restrict__ hb1,
    const float* __restrict__ hb2, const float* __restrict__ hb3,
    const float* __restrict__ misc, float* __restrict__ out, int Q)
{
    int t = threadIdx.x;
    int wave = t >> 6, lane = t & 63;
    int q = blockIdx.x * 4 + wave;
    if (q >= Q) return;
    const float* a3 = h3f + (size_t)q * HID;
    const float* b1 = hb1 + (size_t)q * HID;
    const float* b2 = hb2 + (size_t)q * HID;
    const float* b3 = hb3 + (size_t)q * HID;
    const float* h1c = misc + 128;
    const float* h2c = misc + 480;
    float sA = 0, sB = 0, s3 = 0, s4 = 0, s5 = 0, s6 = 0, s7 = 0, s8 = 0, s9 = 0, s10 = 0;
    for (int hh = lane; hh < HID; hh += 64) {
        float a = a3[hh], b = b1[hh], v2 = b2[hh], v3 = b3[hh];
        float u1 = h1c[hh], u2 = h2c[hh];
        sA += u1 * a;  sB += u2 * a;
        s3 += a * a;   s4 += b * b;
        s5 += v3 * b;  s6 += v2 * b;
        s7 += v3 * v3; s8 += v2 * v2;
        s9 += u1 * u1; s10 += u2 * u2;
    }
#pragma unroll
    for (int off = 32; off > 0; off >>= 1) {
        sA += __shfl_xor(sA, off);  sB += __shfl_xor(sB, off);
        s3 += __shfl_xor(s3, off);  s4 += __shfl_xor(s4, off);
        s5 += __shfl_xor(s5, off);  s6 += __shfl_xor(s6, off);
        s7 += __shfl_xor(s7, off);  s8 += __shfl_xor(s8, off);
        s9 += __shfl_xor(s9, off);  s10 += __shfl_xor(s10, off);
    }
    if (lane == 0) {
        float nq  = fmaxf(sqrtf(s3 + s4), 1e-8f);
        float ns0 = fmaxf(sqrtf(s9 + s7), 1e-8f);
        float ns1 = fmaxf(sqrtf(s10 + s8), 1e-8f);
        float sim0 = (sA + s5) / (ns0 * nq);
        float sim1 = (sB + s6) / (ns1 * nq);
        float mx = fmaxf(sim0, sim1);
        float e0 = __expf(sim0 - mx), e1 = __expf(sim1 - mx);
        float inv = 1.f / (e0 + e1);
        out[(size_t)q * 2 + 0] = e0 * inv;
        out[(size_t)q * 2 + 1] = e1 * inv;
    }
}

extern "C" void kernel_launch(void* const* d_in, const int* in_sizes, int n_in,
                              void* d_out, int out_size, void* d_ws, size_t ws_size,
                              hipStream_t stream)
{
    const float* x    = (const float*)d_in[0];
    const float* c1w  = (const float*)d_in[1];
    const float* c1b  = (const float*)d_in[2];
    const float* bn1g = (const float*)d_in[3];
    const float* bn1b = (const float*)d_in[4];
    const float* c2w  = (const float*)d_in[5];
    const float* c2b  = (const float*)d_in[6];
    const float* bn2g = (const float*)d_in[7];
    const float* bn2b = (const float*)d_in[8];
    const float* wihf = (const float*)d_in[9];
    const float* whhf = (const float*)d_in[10];
    const float* bihf = (const float*)d_in[11];
    const float* bhhf = (const float*)d_in[12];
    const float* wihr = (const float*)d_in[13];
    const float* whhr = (const float*)d_in[14];
    const float* bihr = (const float*)d_in[15];
    const float* bhhr = (const float*)d_in[16];

    int N = in_sizes[0] / LIN;
    int Q = N - NSUP;

    char* ws = (char*)d_ws;
    float* part1 = (float*)ws;                    // 1024*64 f32
    float* part2 = (float*)(ws + 262144);         // 1024*64 f32
    float* misc  = (float*)(ws + 524288);         // ~6816 f32
    float* z     = (float*)(ws + 1048576);        // N*352 f32  (~23.1 MB)
    const size_t A0 = 25165824;                   // big-array region
    const size_t S  = (size_t)Q * HID * sizeof(float);
    float* h3f = (float*)(ws + A0);
    float* hb1 = (float*)(ws + A0 + S);
    float* cb1 = (float*)(ws + A0 + 2 * S);
    float* hb2 = (float*)(ws + A0 + 3 * S);
    float* cb2 = (float*)(ws + A0 + 4 * S);
    float* hb3 = (float*)(ws + A0 + 5 * S);
    float* h1  = (float*)(ws + A0);               // alias: h1 (N*32*59) dead before h3f written

    conv1_stats<<<1024, 256, 0, stream>>>(x, c1w, c1b, part1, N);
    finalize_stats<<<1, 32, 0, stream>>>(part1, misc + 0, misc + 32, (double)N * L1C, 1024);
    conv1_apply<<<N, 256, 0, stream>>>(x, c1w, c1b, bn1g, bn1b, misc + 0, misc + 32, h1, N);
    conv2_stats<<<1024, 256, 0, stream>>>(h1, c2w, c2b, part2, N);
    finalize_stats<<<1, 32, 0, stream>>>(part2, misc + 64, misc + 96, (double)N * L2C, 1024);
    conv2_apply<<<N, 256, 0, stream>>>(h1, c2w, c2b, bn2g, bn2b, misc + 64, misc + 96, z, N);
    small_precompute<<<1, 256, 0, stream>>>(z, wihf, whhf, bihf, bhhf, wihr, bihr, bhhr, misc);

    const float* zq = z + (size_t)NSUP * VEC;
    dim3 gg((Q + 127) / 128, 22);
    // forward step2: gates = query@Wih_f^T + gf_const ; c_prev = c2_f (const vec)
    lstm_gemm_cell<<<gg, 256, 0, stream>>>(zq, wihf, misc + 1184, misc + 832, 1, h3f, nullptr, Q);
    // backward step0: gates = query@Wih_r^T + (b_ih_r+b_hh_r) ; c_prev = 0
    lstm_gemm_cell<<<gg, 256, 0, stream>>>(zq, wihr, misc + 2592, nullptr, 0, hb1, cb1, Q);
    // backward step1: gates = hb1@Whh_r^T + pre_s1 ; c_prev = cb1
    lstm_gemm_cell<<<gg, 256, 0, stream>>>(hb1, whhr, misc + 4000, cb1, 2, hb2, cb2, Q);
    // backward step2: gates = hb2@Whh_r^T + pre_s0 ; c_prev = cb2
    lstm_gemm_cell<<<gg, 256, 0, stream>>>(hb2, whhr, misc + 5408, cb2, 2, hb3, nullptr, Q);

    final_sims<<<(Q + 3) / 4, 256, 0, stream>>>(h3f, hb1, hb2, hb3, misc, (float*)d_out, Q);
}

// Round 2
// 610.920 us; speedup vs baseline: 5.9900x; 5.9900x over previous
//
#include <hip/hip_runtime.h>
#include <hip/hip_bf16.h>

#define NSUP 20
#define VEC 352
#define HID 352
#define GATES 1408
#define LIN 300
#define L1C 298
#define P1 59
#define L2C 57
#define P2 11

typedef __attribute__((ext_vector_type(8))) short short8v;
typedef __attribute__((ext_vector_type(4))) float float4v;

__device__ __forceinline__ float sigf(float x) { return 1.0f / (1.0f + __expf(-x)); }

__device__ __forceinline__ unsigned short f2bf(float x) {
    union { float f; unsigned u; } v; v.f = x;
    unsigned r = v.u + 0x7fffu + ((v.u >> 16) & 1u);
    return (unsigned short)(r >> 16);
}
__device__ __forceinline__ float bf2f(unsigned short s) {
    union { unsigned u; float f; } v; v.u = ((unsigned)s) << 16; return v.f;
}

// ---------------- cast weights to bf16 (+ w2 transpose to [kk][c][ci]) ----------------
__global__ __launch_bounds__(256) void cast_weights(
    const float* __restrict__ wihf, const float* __restrict__ wihr,
    const float* __restrict__ whhr, const float* __restrict__ w2,
    unsigned short* __restrict__ wihf_b, unsigned short* __restrict__ wihr_b,
    unsigned short* __restrict__ whhr_b, unsigned short* __restrict__ w2t)
{
    const int NW = GATES * VEC;
    int i = blockIdx.x * 256 + threadIdx.x;
    if (i < NW) wihf_b[i] = f2bf(wihf[i]);
    else if (i < 2 * NW) wihr_b[i - NW] = f2bf(wihr[i - NW]);
    else if (i < 3 * NW) whhr_b[i - 2 * NW] = f2bf(whhr[i - 2 * NW]);
    else if (i < 3 * NW + 5120) {
        int j = i - 3 * NW;
        int kk = j >> 10, c = (j >> 5) & 31, ci = j & 31;
        w2t[j] = f2bf(w2[c * 160 + ci * 5 + kk]);
    }
}

// ---------------- conv1: stats + pooled raw max -> h1 (bf16 [n][64][32], row=l+1) ----------------
__global__ __launch_bounds__(256) void conv1_pass1(const float* __restrict__ x,
    const float* __restrict__ w, const float* __restrict__ bias,
    float* __restrict__ part, unsigned short* __restrict__ h1, int N)
{
    int t = threadIdx.x;
    int wv = t >> 6, lane = t & 63;
    int c = lane & 31, half = lane >> 5;
    float wr[5];
#pragma unroll
    for (int k = 0; k < 5; ++k) wr[k] = w[c * 5 + k];
    float b = bias[c];
    float sum = 0.f, sq = 0.f;
    for (int n = blockIdx.x * 4 + wv; n < N; n += gridDim.x * 4) {
        const float* xr = x + (size_t)n * LIN;
        unsigned short* hr = h1 + (size_t)n * 2048;
        int b0 = half ? 8 : 0, b1 = half ? 15 : 8;
        for (int bb = b0; bb < b1; ++bb) {
            float xv[28];
            int base = bb * 20 - 4;
#pragma unroll
            for (int v8 = 0; v8 < 7; ++v8) {
                int bs = base + v8 * 4;
                if (bs >= 0 && bs + 3 < LIN) {
                    float4 q4 = *(const float4*)(xr + bs);
                    xv[v8 * 4 + 0] = q4.x; xv[v8 * 4 + 1] = q4.y;
                    xv[v8 * 4 + 2] = q4.z; xv[v8 * 4 + 3] = q4.w;
                } else {
#pragma unroll
                    for (int e = 0; e < 4; ++e) {
                        int ix = bs + e;
                        xv[v8 * 4 + e] = (ix >= 0 && ix < LIN) ? xr[ix] : 0.f;
                    }
                }
            }
#pragma unroll
            for (int grp = 0; grp < 4; ++grp) {
                int lo = bb * 4 + grp;
                float m = -1e30f;
#pragma unroll
                for (int d5 = 0; d5 < 5; ++d5) {
                    int dj = grp * 5 + d5;
                    int j = bb * 20 + dj;
                    if (j <= 297) {
                        float y = b;
#pragma unroll
                        for (int k = 0; k < 5; ++k) y = fmaf(wr[k], xv[dj + 3 + k], y);
                        sum += y; sq = fmaf(y, y, sq);
                        m = fmaxf(m, y);
                    }
                }
                if (lo <= 58) hr[(1 + lo) * 32 + c] = f2bf(m);
            }
        }
        if (half == 0) hr[c] = 0;
        else { hr[60 * 32 + c] = 0; hr[61 * 32 + c] = 0; hr[62 * 32 + c] = 0; hr[63 * 32 + c] = 0; }
    }
    __shared__ float redS[256], redQ[256];
    redS[t] = sum; redQ[t] = sq;
    __syncthreads();
    if (t < 32) {
        float s = 0.f, q = 0.f;
#pragma unroll
        for (int m = 0; m < 8; ++m) { s += redS[m * 32 + t]; q += redQ[m * 32 + t]; }
        part[blockIdx.x * 64 + t] = s;
        part[blockIdx.x * 64 + 32 + t] = q;
    }
}

__global__ void finalize_stats2(const float* __restrict__ part, float* __restrict__ outM,
    float* __restrict__ outI, float count)
{
    __shared__ float fin[64];
    int t = threadIdx.x;  // 64 threads
    float s = 0.f;
    for (int b = 0; b < 256; ++b) s += part[b * 64 + t];
    fin[t] = s;
    __syncthreads();
    if (t < 32) {
        double m = (double)fin[t] / (double)count;
        double v = (double)fin[32 + t] / (double)count - m * m;
        outM[t] = (float)m;
        outI[t] = (float)(1.0 / sqrt(v + 1e-5));
    }
}

// ---------------- conv1 pass2: in-place BN+relu on pooled raw (rows 1..59) ----------------
__global__ __launch_bounds__(256) void conv1_pass2(unsigned short* __restrict__ h1,
    const float* __restrict__ mean, const float* __restrict__ istd,
    const float* __restrict__ g1, const float* __restrict__ b1n, long long total)
{
    __shared__ float sc[32], sh[32];
    int t = threadIdx.x;
    if (t < 32) { float s = istd[t] * g1[t]; sc[t] = s; sh[t] = b1n[t] - mean[t] * s; }
    __syncthreads();
    long long i = (long long)blockIdx.x * 256 + t;
    if (i >= total) return;
    long long n = i / 236; int r = (int)(i % 236);
    int row = 1 + (r >> 2), c0 = (r & 3) * 8;
    unsigned short* p = h1 + n * 2048 + row * 32 + c0;
    union { uint4 v; unsigned short u[8]; } d;
    d.v = *(const uint4*)p;
#pragma unroll
    for (int e = 0; e < 8; ++e) {
        int c = c0 + e;
        float y = fmaf(sc[c], bf2f(d.u[e]), sh[c]);
        d.u[e] = f2bf(fmaxf(y, 0.f));
    }
    *(uint4*)p = d.v;
}

// ---------------- conv2 stats via MFMA ----------------
__global__ __launch_bounds__(256) void conv2_stats_mfma(const unsigned short* __restrict__ h1,
    const unsigned short* __restrict__ w2t, const float* __restrict__ b2,
    float* __restrict__ part, int N)
{
    int t = threadIdx.x, wv = t >> 6, lane = t & 63;
    int li = lane & 15, grp = lane >> 4;
    short8v af[5][2];
#pragma unroll
    for (int kk = 0; kk < 5; ++kk)
#pragma unroll
        for (int mf = 0; mf < 2; ++mf)
            af[kk][mf] = *(const short8v*)(w2t + ((kk * 32 + mf * 16 + li) * 32 + grp * 8));
    float bc[2][4];
#pragma unroll
    for (int mf = 0; mf < 2; ++mf)
#pragma unroll
        for (int r = 0; r < 4; ++r) bc[mf][r] = b2[mf * 16 + grp * 4 + r];
    float sum[2][4] = {}, sq[2][4] = {};
    for (int n = blockIdx.x * 4 + wv; n < N; n += gridDim.x * 4) {
        const unsigned short* hb = h1 + (size_t)n * 2048;
#pragma unroll
        for (int lt = 0; lt < 4; ++lt) {
            float4v acc0 = {0.f, 0.f, 0.f, 0.f}, acc1 = {0.f, 0.f, 0.f, 0.f};
#pragma unroll
            for (int kk = 0; kk < 5; ++kk) {
                int row = lt * 16 + li + kk; row = row > 63 ? 63 : row;
                short8v bf = *(const short8v*)(hb + row * 32 + grp * 8);
                acc0 = __builtin_amdgcn_mfma_f32_16x16x32_bf16(af[kk][0], bf, acc0, 0, 0, 0);
                acc1 = __builtin_amdgcn_mfma_f32_16x16x32_bf16(af[kk][1], bf, acc1, 0, 0, 0);
            }
            if (lt * 16 + li < L2C) {
#pragma unroll
                for (int r = 0; r < 4; ++r) {
                    float y0 = acc0[r] + bc[0][r]; sum[0][r] += y0; sq[0][r] = fmaf(y0, y0, sq[0][r]);
                    float y1 = acc1[r] + bc[1][r]; sum[1][r] += y1; sq[1][r] = fmaf(y1, y1, sq[1][r]);
                }
            }
        }
    }
    __shared__ float redS[4][32], redQ[4][32];
#pragma unroll
    for (int mf = 0; mf < 2; ++mf)
#pragma unroll
        for (int r = 0; r < 4; ++r) {
            float s = sum[mf][r], q = sq[mf][r];
#pragma unroll
            for (int m = 1; m < 16; m <<= 1) { s += __shfl_xor(s, m); q += __shfl_xor(q, m); }
            if (li == 0) { redS[wv][mf * 16 + grp * 4 + r] = s; redQ[wv][mf * 16 + grp * 4 + r] = q; }
        }
    __syncthreads();
    if (t < 32) part[blockIdx.x * 64 + t] = redS[0][t] + redS[1][t] + redS[2][t] + redS[3][t];
    else if (t < 64) part[blockIdx.x * 64 + t] = redQ[0][t - 32] + redQ[1][t - 32] + redQ[2][t - 32] + redQ[3][t - 32];
}

// ---------------- conv2 apply via MFMA + BN + relu + pool -> z bf16 [n][352] ----------------
__global__ __launch_bounds__(256) void conv2_apply_mfma(const unsigned short* __restrict__ h1,
    const unsigned short* __restrict__ w2t, const float* __restrict__ b2,
    const float* __restrict__ mean, const float* __restrict__ istd,
    const float* __restrict__ g2, const float* __restrict__ be2,
    unsigned short* __restrict__ z, int N)
{
    __shared__ float yt[4][32][66];
    __shared__ float sc2[32], sh2[32], bcv[32];
    int t = threadIdx.x, wv = t >> 6, lane = t & 63;
    int li = lane & 15, grp = lane >> 4;
    if (t < 32) { float s = istd[t] * g2[t]; sc2[t] = s; sh2[t] = be2[t] - mean[t] * s; bcv[t] = b2[t]; }
    short8v af[5][2];
#pragma unroll
    for (int kk = 0; kk < 5; ++kk)
#pragma unroll
        for (int mf = 0; mf < 2; ++mf)
            af[kk][mf] = *(const short8v*)(w2t + ((kk * 32 + mf * 16 + li) * 32 + grp * 8));
    __syncthreads();
    for (int n = blockIdx.x * 4 + wv; n < N; n += gridDim.x * 4) {
        const unsigned short* hb = h1 + (size_t)n * 2048;
#pragma unroll
        for (int lt = 0; lt < 4; ++lt) {
            float4v acc0 = {0.f, 0.f, 0.f, 0.f}, acc1 = {0.f, 0.f, 0.f, 0.f};
#pragma unroll
            for (int kk = 0; kk < 5; ++kk) {
                int row = lt * 16 + li + kk; row = row > 63 ? 63 : row;
                short8v bf = *(const short8v*)(hb + row * 32 + grp * 8);
                acc0 = __builtin_amdgcn_mfma_f32_16x16x32_bf16(af[kk][0], bf, acc0, 0, 0, 0);
                acc1 = __builtin_amdgcn_mfma_f32_16x16x32_bf16(af[kk][1], bf, acc1, 0, 0, 0);
            }
#pragma unroll
            for (int r = 0; r < 4; ++r) {
                yt[wv][grp * 4 + r][lt * 16 + li] = acc0[r];
                yt[wv][16 + grp * 4 + r][lt * 16 + li] = acc1[r];
            }
        }
        unsigned short* zr = z + (size_t)n * VEC;
        for (int s = lane; s < VEC; s += 64) {
            int c = s / 11, lo = s % 11;
            float m = yt[wv][c][lo * 5];
#pragma unroll
            for (int d = 1; d < 5; ++d) m = fmaxf(m, yt[wv][c][lo * 5 + d]);
            float y = fmaf(sc2[c], m + bcv[c], sh2[c]);
            zr[s] = f2bf(fmaxf(y, 0.f));
        }
    }
}

// ---------------- support means ----------------
__global__ void sup_means(const unsigned short* __restrict__ z, float* __restrict__ misc)
{
    int v = blockIdx.x * 64 + threadIdx.x;
    if (v >= VEC) return;
    float s0 = 0.f, s1 = 0.f;
    for (int k = 0; k < 10; ++k) {
        s0 += bf2f(z[(size_t)k * VEC + v]);
        s1 += bf2f(z[(size_t)(10 + k) * VEC + v]);
    }
    misc[128 + v] = s0 * 0.1f;
    misc[480 + v] = s1 * 0.1f;
}

// ---------------- support-path gate GEMVs (fp32) ----------------
__global__ __launch_bounds__(128) void gates_gemv(int mode,
    const float* __restrict__ wihf, const float* __restrict__ whhf,
    const float* __restrict__ bihf, const float* __restrict__ bhhf,
    const float* __restrict__ wihr, const float* __restrict__ bihr,
    const float* __restrict__ bhhr, float* __restrict__ misc)
{
    __shared__ float s0[VEC], s1[VEC], h1f[VEC], h2f[VEC];
    int t = threadIdx.x;
    for (int i = t; i < VEC; i += 128) {
        s0[i] = misc[128 + i]; s1[i] = misc[480 + i];
        h1f[i] = misc[832 + i]; h2f[i] = misc[1536 + i];
    }
    __syncthreads();
    int j = blockIdx.x * 128 + t;
    if (j >= GATES) return;
    if (mode == 0) {
        float a = bihf[j] + bhhf[j];
        const float* w = wihf + (size_t)j * VEC;
        for (int k = 0; k < VEC; k += 4)
            a += w[k] * s0[k] + w[k + 1] * s0[k + 1] + w[k + 2] * s0[k + 2] + w[k + 3] * s0[k + 3];
        misc[2240 + j] = a;
    } else if (mode == 1) {
        float a = bihf[j] + bhhf[j];
        const float* w = wihf + (size_t)j * VEC;
        const float* wh = whhf + (size_t)j * VEC;
        for (int k = 0; k < VEC; k += 4) {
            a += w[k] * s1[k] + w[k + 1] * s1[k + 1] + w[k + 2] * s1[k + 2] + w[k + 3] * s1[k + 3];
            a += wh[k] * h1f[k] + wh[k + 1] * h1f[k + 1] + wh[k + 2] * h1f[k + 2] + wh[k + 3] * h1f[k + 3];
        }
        misc[3648 + j] = a;
    } else {
        float a = bihf[j] + bhhf[j];
        const float* wh = whhf + (size_t)j * VEC;
        for (int k = 0; k < VEC; k += 4)
            a += wh[k] * h2f[k] + wh[k + 1] * h2f[k + 1] + wh[k + 2] * h2f[k + 2] + wh[k + 3] * h2f[k + 3];
        misc[5056 + j] = a;
        float br = bihr[j] + bhhr[j];
        const float* wr = wihr + (size_t)j * VEC;
        float p1 = br, p0 = br;
        for (int k = 0; k < VEC; k += 4) {
            p1 += wr[k] * s1[k] + wr[k + 1] * s1[k + 1] + wr[k + 2] * s1[k + 2] + wr[k + 3] * s1[k + 3];
            p0 += wr[k] * s0[k] + wr[k + 1] * s0[k + 1] + wr[k + 2] * s0[k + 2] + wr[k + 3] * s0[k + 3];
        }
        misc[6464 + j] = p1;
        misc[7872 + j] = p0;
    }
}

__global__ void cell_small(const float* __restrict__ g, const float* __restrict__ cp,
    float* __restrict__ ho, float* __restrict__ co)
{
    int h = blockIdx.x * 64 + threadIdx.x;
    if (h >= HID) return;
    float iv = sigf(g[h]), fv = sigf(g[HID + h]);
    float gv = tanhf(g[2 * HID + h]), ov = sigf(g[3 * HID + h]);
    float c = iv * gv + (cp ? fv * cp[h] : 0.f);
    ho[h] = ov * tanhf(c);
    co[h] = c;
}

// ---------------- big LSTM step: bf16 MFMA GEMM + fused cell ----------------
// gates[q][g] = X[q]·Wb[g] + add1[g] (+ add2[g]); cell with cprev per cmode.
__global__ __launch_bounds__(256) void lstm_mfma(
    const unsigned short* __restrict__ Xb, const unsigned short* __restrict__ Wb,
    const float* __restrict__ add1, const float* __restrict__ add2,
    const float* __restrict__ cprev, int cmode,
    float* __restrict__ hf, unsigned short* __restrict__ hbf, float* __restrict__ cf, int Q)
{
    int t = threadIdx.x, wv = t >> 6, lane = t & 63;
    int li = lane & 15, grp = lane >> 4;
    int q0 = blockIdx.x * 256 + wv * 64;
    int h0 = blockIdx.y * 16;
    int h = h0 + li;
    const unsigned short* xp[4];
#pragma unroll
    for (int mf = 0; mf < 4; ++mf) {
        int qr = q0 + mf * 16 + li;
        if (qr > Q - 1) qr = Q - 1;
        xp[mf] = Xb + (size_t)qr * VEC + grp * 8;
    }
    const unsigned short* wbase = Wb + (size_t)(h0 + li) * VEC + grp * 8;
    float4v acc[4][4];
#pragma unroll
    for (int gi = 0; gi < 4; ++gi)
#pragma unroll
        for (int mf = 0; mf < 4; ++mf) acc[gi][mf] = (float4v){0.f, 0.f, 0.f, 0.f};
#pragma unroll 2
    for (int ks = 0; ks < 11; ++ks) {
        int ko = ks * 32;
        short8v a0 = *(const short8v*)(xp[0] + ko);
        short8v a1 = *(const short8v*)(xp[1] + ko);
        short8v a2 = *(const short8v*)(xp[2] + ko);
        short8v a3 = *(const short8v*)(xp[3] + ko);
        short8v b0 = *(const short8v*)(wbase + ko);
        short8v b1 = *(const short8v*)(wbase + (size_t)HID * VEC + ko);
        short8v b2 = *(const short8v*)(wbase + (size_t)2 * HID * VEC + ko);
        short8v b3 = *(const short8v*)(wbase + (size_t)3 * HID * VEC + ko);
        acc[0][0] = __builtin_amdgcn_mfma_f32_16x16x32_bf16(a0, b0, acc[0][0], 0, 0, 0);
        acc[0][1] = __builtin_amdgcn_mfma_f32_16x16x32_bf16(a1, b0, acc[0][1], 0, 0, 0);
        acc[0][2] = __builtin_amdgcn_mfma_f32_16x16x32_bf16(a2, b0, acc[0][2], 0, 0, 0);
        acc[0][3] = __builtin_amdgcn_mfma_f32_16x16x32_bf16(a3, b0, acc[0][3], 0, 0, 0);
        acc[1][0] = __builtin_amdgcn_mfma_f32_16x16x32_bf16(a0, b1, acc[1][0], 0, 0, 0);
        acc[1][1] = __builtin_amdgcn_mfma_f32_16x16x32_bf16(a1, b1, acc[1][1], 0, 0, 0);
        acc[1][2] = __builtin_amdgcn_mfma_f32_16x16x32_bf16(a2, b1, acc[1][2], 0, 0, 0);
        acc[1][3] = __builtin_amdgcn_mfma_f32_16x16x32_bf16(a3, b1, acc[1][3], 0, 0, 0);
        acc[2][0] = __builtin_amdgcn_mfma_f32_16x16x32_bf16(a0, b2, acc[2][0], 0, 0, 0);
        acc[2][1] = __builtin_amdgcn_mfma_f32_16x16x32_bf16(a1, b2, acc[2][1], 0, 0, 0);
        acc[2][2] = __builtin_amdgcn_mfma_f32_16x16x32_bf16(a2, b2, acc[2][2], 0, 0, 0);
        acc[2][3] = __builtin_amdgcn_mfma_f32_16x16x32_bf16(a3, b2, acc[2][3], 0, 0, 0);
        acc[3][0] = __builtin_amdgcn_mfma_f32_16x16x32_bf16(a0, b3, acc[3][0], 0, 0, 0);
        acc[3][1] = __builtin_amdgcn_mfma_f32_16x16x32_bf16(a1, b3, acc[3][1], 0, 0, 0);
        acc[3][2] = __builtin_amdgcn_mfma_f32_16x16x32_bf16(a2, b3, acc[3][2], 0, 0, 0);
        acc[3][3] = __builtin_amdgcn_mfma_f32_16x16x32_bf16(a3, b3, acc[3][3], 0, 0, 0);
    }
    float ai = add1[h] + (add2 ? add2[h] : 0.f);
    float afv = add1[HID + h] + (add2 ? add2[HID + h] : 0.f);
    float ag = add1[2 * HID + h] + (add2 ? add2[2 * HID + h] : 0.f);
    float ao = add1[3 * HID + h] + (add2 ? add2[3 * HID + h] : 0.f);
    float cc1 = (cmode == 1) ? cprev[h] : 0.f;
#pragma unroll
    for (int mf = 0; mf < 4; ++mf) {
#pragma unroll
        for (int r = 0; r < 4; ++r) {
            int q = q0 + mf * 16 + grp * 4 + r;
            if (q >= Q) continue;
            float iv = sigf(acc[0][mf][r] + ai);
            float fv = sigf(acc[1][mf][r] + afv);
            float gv = tanhf(acc[2][mf][r] + ag);
            float ov = sigf(acc[3][mf][r] + ao);
            float cp = (cmode == 2) ? cprev[(size_t)q * HID + h] : cc1;
            float cn = fv * cp + iv * gv;
            float hn = ov * tanhf(cn);
            hf[(size_t)q * HID + h] = hn;
            if (hbf) hbf[(size_t)q * HID + h] = f2bf(hn);
            if (cf) cf[(size_t)q * HID + h] = cn;
        }
    }
}

// ---------------- cosine sims + softmax; one wave per query ----------------
__global__ __launch_bounds__(256) void final_sims(
    const float* __restrict__ h3f, const float* __restrict__ hb1,
    const float* __restrict__ hb2, const float* __restrict__ hb3,
    const float* __restrict__ misc, float* __restrict__ out, int Q)
{
    int t = threadIdx.x;
    int wave = t >> 6, lane = t & 63;
    int q = blockIdx.x * 4 + wave;
    if (q >= Q) return;
    const float* a3 = h3f + (size_t)q * HID;
    const float* b1 = hb1 + (size_t)q * HID;
    const float* b2 = hb2 + (size_t)q * HID;
    const float* b3 = hb3 + (size_t)q * HID;
    const float* h1c = misc + 832;
    const float* h2c = misc + 1536;
    float sA = 0, sB = 0, s3 = 0, s4 = 0, s5 = 0, s6 = 0, s7 = 0, s8 = 0, s9 = 0, s10 = 0;
    for (int hh = lane; hh < HID; hh += 64) {
        float a = a3[hh], b = b1[hh], v2 = b2[hh], v3 = b3[hh];
        float u1 = h1c[hh], u2 = h2c[hh];
        sA += u1 * a;  sB += u2 * a;
        s3 += a * a;   s4 += b * b;
        s5 += v3 * b;  s6 += v2 * b;
        s7 += v3 * v3; s8 += v2 * v2;
        s9 += u1 * u1; s10 += u2 * u2;
    }
#pragma unroll
    for (int off = 32; off > 0; off >>= 1) {
        sA += __shfl_xor(sA, off);  sB += __shfl_xor(sB, off);
        s3 += __shfl_xor(s3, off);  s4 += __shfl_xor(s4, off);
        s5 += __shfl_xor(s5, off);  s6 += __shfl_xor(s6, off);
        s7 += __shfl_xor(s7, off);  s8 += __shfl_xor(s8, off);
        s9 += __shfl_xor(s9, off);  s10 += __shfl_xor(s10, off);
    }
    if (lane == 0) {
        float nq  = fmaxf(sqrtf(s3 + s4), 1e-8f);
        float ns0 = fmaxf(sqrtf(s9 + s7), 1e-8f);
        float ns1 = fmaxf(sqrtf(s10 + s8), 1e-8f);
        float sim0 = (sA + s5) / (ns0 * nq);
        float sim1 = (sB + s6) / (ns1 * nq);
        float mx = fmaxf(sim0, sim1);
        float e0 = __expf(sim0 - mx), e1 = __expf(sim1 - mx);
        float inv = 1.f / (e0 + e1);
        out[(size_t)q * 2 + 0] = e0 * inv;
        out[(size_t)q * 2 + 1] = e1 * inv;
    }
}

extern "C" void kernel_launch(void* const* d_in, const int* in_sizes, int n_in,
                              void* d_out, int out_size, void* d_ws, size_t ws_size,
                              hipStream_t stream)
{
    const float* x    = (const float*)d_in[0];
    const float* c1w  = (const float*)d_in[1];
    const float* c1b  = (const float*)d_in[2];
    const float* bn1g = (const float*)d_in[3];
    const float* bn1b = (const float*)d_in[4];
    const float* c2w  = (const float*)d_in[5];
    const float* c2b  = (const float*)d_in[6];
    const float* bn2g = (const float*)d_in[7];
    const float* bn2b = (const float*)d_in[8];
    const float* wihf = (const float*)d_in[9];
    const float* whhf = (const float*)d_in[10];
    const float* bihf = (const float*)d_in[11];
    const float* bhhf = (const float*)d_in[12];
    const float* wihr = (const float*)d_in[13];
    const float* whhr = (const float*)d_in[14];
    const float* bihr = (const float*)d_in[15];
    const float* bhhr = (const float*)d_in[16];

    int N = in_sizes[0] / LIN;
    int Q = N - NSUP;

    char* ws = (char*)d_ws;
    float* part1 = (float*)(ws + 0);                       // 256*64 f32
    float* part2 = (float*)(ws + 65536);                   // 256*64 f32
    float* misc  = (float*)(ws + 131072);                  // ~9.3K f32
    unsigned short* w2t    = (unsigned short*)(ws + 196608);       // 5120 bf16
    unsigned short* wihf_b = (unsigned short*)(ws + 1048576);
    unsigned short* wihr_b = (unsigned short*)(ws + 2097152);
    unsigned short* whhr_b = (unsigned short*)(ws + 3145728);
    unsigned short* z      = (unsigned short*)(ws + 5242880);      // N*352 bf16
    unsigned short* h1     = (unsigned short*)(ws + 17825792);     // N*64*32 bf16 (dead after conv2)
    const size_t S4 = (size_t)Q * HID * sizeof(float);
    float* h3f = (float*)(ws + 17825792);                  // over h1 (dead)
    float* hb1 = (float*)(ws + 17825792 + S4);
    unsigned short* hb1b = (unsigned short*)(ws + 17825792 + 2 * S4);
    float* cb1 = (float*)(ws + 17825792 + 2 * S4 + S4 / 2);
    float* hb2 = (float*)(ws + 17825792 + 3 * S4 + S4 / 2);
    unsigned short* hb2b = (unsigned short*)(ws + 17825792 + 4 * S4 + S4 / 2);
    float* cb2 = (float*)(ws + 17825792 + 5 * S4);
    float* hb3 = (float*)(ws + 17825792 + 2 * S4);         // over hb1b+cb1 (dead after GEMM3)

    // 1. cast weights
    {
        int tot = 3 * GATES * VEC + 5120;
        cast_weights<<<(tot + 255) / 256, 256, 0, stream>>>(wihf, wihr, whhr, c2w,
                                                            wihf_b, wihr_b, whhr_b, w2t);
    }
    // 2. conv1: stats + pooled raw
    conv1_pass1<<<256, 256, 0, stream>>>(x, c1w, c1b, part1, h1, N);
    finalize_stats2<<<1, 64, 0, stream>>>(part1, misc + 0, misc + 32, (float)((long long)N * L1C));
    // 3. conv1 BN+relu in place
    {
        long long total = (long long)N * 236;
        conv1_pass2<<<(unsigned)((total + 255) / 256), 256, 0, stream>>>(h1, misc + 0, misc + 32, bn1g, bn1b, total);
    }
    // 4. conv2 stats
    conv2_stats_mfma<<<256, 256, 0, stream>>>(h1, w2t, c2b, part2, N);
    finalize_stats2<<<1, 64, 0, stream>>>(part2, misc + 64, misc + 96, (float)((long long)N * L2C));
    // 5. conv2 apply -> z
    conv2_apply_mfma<<<256, 256, 0, stream>>>(h1, w2t, c2b, misc + 64, misc + 96, bn2g, bn2b, z, N);
    // 6. support path
    sup_means<<<6, 64, 0, stream>>>(z, misc);
    gates_gemv<<<11, 128, 0, stream>>>(0, wihf, whhf, bihf, bhhf, wihr, bihr, bhhr, misc);
    cell_small<<<6, 64, 0, stream>>>(misc + 2240, nullptr, misc + 832, misc + 1184);
    gates_gemv<<<11, 128, 0, stream>>>(1, wihf, whhf, bihf, bhhf, wihr, bihr, bhhr, misc);
    cell_small<<<6, 64, 0, stream>>>(misc + 3648, misc + 1184, misc + 1536, misc + 1888);
    gates_gemv<<<11, 128, 0, stream>>>(2, wihf, whhf, bihf, bhhf, wihr, bihr, bhhr, misc);
    // 7. big LSTM steps
    const unsigned short* zq = z + (size_t)NSUP * VEC;
    dim3 gg((Q + 255) / 256, 22);
    // fwd step2: gates = zq@Wihf^T + gf_const ; cprev = c2f (const vec)
    lstm_mfma<<<gg, 256, 0, stream>>>(zq, wihf_b, misc + 5056, nullptr, misc + 1888, 1, h3f, nullptr, nullptr, Q);
    // bwd step0: gates = zq@Wihr^T + (bihr+bhhr) ; cprev = 0
    lstm_mfma<<<gg, 256, 0, stream>>>(zq, wihr_b, bihr, bhhr, nullptr, 0, hb1, hb1b, cb1, Q);
    // bwd step1: gates = hb1@Whhr^T + pre_s1 ; cprev = cb1
    lstm_mfma<<<gg, 256, 0, stream>>>(hb1b, whhr_b, misc + 6464, nullptr, cb1, 2, hb2, hb2b, cb2, Q);
    // bwd step2: gates = hb2@Whhr^T + pre_s0 ; cprev = cb2
    lstm_mfma<<<gg, 256, 0, stream>>>(hb2b, whhr_b, misc + 7872, nullptr, cb2, 2, hb3, nullptr, nullptr, Q);
    // 8. sims + softmax
    final_sims<<<(Q + 3) / 4, 256, 0, stream>>>(h3f, hb1, hb2, hb3, misc, (float*)d_out, Q);
}

// Round 3
// 569.699 us; speedup vs baseline: 6.4234x; 1.0724x over previous
//
#include <hip/hip_runtime.h>
#include <hip/hip_bf16.h>

#define NSUP 20
#define VEC 352
#define HID 352
#define GATES 1408
#define LIN 300
#define L1C 298
#define P1 59
#define L2C 57
#define P2 11
#define NBLK 2048   // grid for grid-stride stats/apply kernels

typedef __attribute__((ext_vector_type(8))) short short8v;
typedef __attribute__((ext_vector_type(4))) float float4v;

__device__ __forceinline__ float sigf(float x) { return 1.0f / (1.0f + __expf(-x)); }

__device__ __forceinline__ unsigned short f2bf(float x) {
    union { float f; unsigned u; } v; v.f = x;
    unsigned r = v.u + 0x7fffu + ((v.u >> 16) & 1u);
    return (unsigned short)(r >> 16);
}
__device__ __forceinline__ float bf2f(unsigned short s) {
    union { unsigned u; float f; } v; v.u = ((unsigned)s) << 16; return v.f;
}

// ---------------- cast weights to bf16 (+ w2 transpose to [kk][c][ci]) ----------------
__global__ __launch_bounds__(256) void cast_weights(
    const float* __restrict__ wihf, const float* __restrict__ wihr,
    const float* __restrict__ whhr, const float* __restrict__ w2,
    unsigned short* __restrict__ wihf_b, unsigned short* __restrict__ wihr_b,
    unsigned short* __restrict__ whhr_b, unsigned short* __restrict__ w2t)
{
    const int NW = GATES * VEC;
    int i = blockIdx.x * 256 + threadIdx.x;
    if (i < NW) wihf_b[i] = f2bf(wihf[i]);
    else if (i < 2 * NW) wihr_b[i - NW] = f2bf(wihr[i - NW]);
    else if (i < 3 * NW) whhr_b[i - 2 * NW] = f2bf(whhr[i - 2 * NW]);
    else if (i < 3 * NW + 5120) {
        int j = i - 3 * NW;
        int kk = j >> 10, c = (j >> 5) & 31, ci = j & 31;
        w2t[j] = f2bf(w2[c * 160 + ci * 5 + kk]);
    }
}

// ---------------- conv1: stats + pooled raw max -> h1 (bf16 [n][64][32], row=l+1) ----------------
__global__ __launch_bounds__(256) void conv1_pass1(const float* __restrict__ x,
    const float* __restrict__ w, const float* __restrict__ bias,
    float* __restrict__ part, unsigned short* __restrict__ h1, int N)
{
    int t = threadIdx.x;
    int wv = t >> 6, lane = t & 63;
    int c = lane & 31, half = lane >> 5;
    float wr[5];
#pragma unroll
    for (int k = 0; k < 5; ++k) wr[k] = w[c * 5 + k];
    float b = bias[c];
    float sum = 0.f, sq = 0.f;
    for (int n = blockIdx.x * 4 + wv; n < N; n += gridDim.x * 4) {
        const float* xr = x + (size_t)n * LIN;
        unsigned short* hr = h1 + (size_t)n * 2048;
        int b0 = half ? 8 : 0, b1 = half ? 15 : 8;
        for (int bb = b0; bb < b1; ++bb) {
            float xv[28];
            int base = bb * 20 - 4;
#pragma unroll
            for (int v8 = 0; v8 < 7; ++v8) {
                int bs = base + v8 * 4;
                if (bs >= 0 && bs + 3 < LIN) {
                    float4 q4 = *(const float4*)(xr + bs);
                    xv[v8 * 4 + 0] = q4.x; xv[v8 * 4 + 1] = q4.y;
                    xv[v8 * 4 + 2] = q4.z; xv[v8 * 4 + 3] = q4.w;
                } else {
#pragma unroll
                    for (int e = 0; e < 4; ++e) {
                        int ix = bs + e;
                        xv[v8 * 4 + e] = (ix >= 0 && ix < LIN) ? xr[ix] : 0.f;
                    }
                }
            }
#pragma unroll
            for (int grp = 0; grp < 4; ++grp) {
                int lo = bb * 4 + grp;
                float m = -1e30f;
#pragma unroll
                for (int d5 = 0; d5 < 5; ++d5) {
                    int dj = grp * 5 + d5;
                    int j = bb * 20 + dj;
                    if (j <= 297) {
                        float y = b;
#pragma unroll
                        for (int k = 0; k < 5; ++k) y = fmaf(wr[k], xv[dj + 3 + k], y);
                        sum += y; sq = fmaf(y, y, sq);
                        m = fmaxf(m, y);
                    }
                }
                if (lo <= 58) hr[(1 + lo) * 32 + c] = f2bf(m);
            }
        }
        if (half == 0) hr[c] = 0;
        else { hr[60 * 32 + c] = 0; hr[61 * 32 + c] = 0; hr[62 * 32 + c] = 0; hr[63 * 32 + c] = 0; }
    }
    __shared__ float redS[256], redQ[256];
    redS[t] = sum; redQ[t] = sq;
    __syncthreads();
    if (t < 32) {
        float s = 0.f, q = 0.f;
#pragma unroll
        for (int m = 0; m < 8; ++m) { s += redS[m * 32 + t]; q += redQ[m * 32 + t]; }
        part[blockIdx.x * 64 + t] = s;
        part[blockIdx.x * 64 + 32 + t] = q;
    }
}

// 512 threads: ch = t&63, grp = t>>6 (8 groups over NBLK blocks)
__global__ __launch_bounds__(512) void finalize_stats2(const float* __restrict__ part,
    float* __restrict__ outM, float* __restrict__ outI, float count)
{
    __shared__ float red[8][64];
    int t = threadIdx.x;
    int ch = t & 63, grp = t >> 6;
    float s = 0.f;
    for (int b = grp; b < NBLK; b += 8) s += part[b * 64 + ch];
    red[grp][ch] = s;
    __syncthreads();
    if (t < 64) {
        float a = 0.f;
#pragma unroll
        for (int g = 0; g < 8; ++g) a += red[g][t];
        red[0][t] = a;
    }
    __syncthreads();
    if (t < 32) {
        double m = (double)red[0][t] / (double)count;
        double v = (double)red[0][32 + t] / (double)count - m * m;
        outM[t] = (float)m;
        outI[t] = (float)(1.0 / sqrt(v + 1e-5));
    }
}

// ---------------- conv1 pass2: in-place BN+relu on pooled raw (rows 1..59) ----------------
__global__ __launch_bounds__(256) void conv1_pass2(unsigned short* __restrict__ h1,
    const float* __restrict__ mean, const float* __restrict__ istd,
    const float* __restrict__ g1, const float* __restrict__ b1n, long long total)
{
    __shared__ float sc[32], sh[32];
    int t = threadIdx.x;
    if (t < 32) { float s = istd[t] * g1[t]; sc[t] = s; sh[t] = b1n[t] - mean[t] * s; }
    __syncthreads();
    long long i = (long long)blockIdx.x * 256 + t;
    if (i >= total) return;
    long long n = i / 236; int r = (int)(i % 236);
    int row = 1 + (r >> 2), c0 = (r & 3) * 8;
    unsigned short* p = h1 + n * 2048 + row * 32 + c0;
    union { uint4 v; unsigned short u[8]; } d;
    d.v = *(const uint4*)p;
#pragma unroll
    for (int e = 0; e < 8; ++e) {
        int c = c0 + e;
        float y = fmaf(sc[c], bf2f(d.u[e]), sh[c]);
        d.u[e] = f2bf(fmaxf(y, 0.f));
    }
    *(uint4*)p = d.v;
}

// ---------------- conv2 stats via MFMA ----------------
__global__ __launch_bounds__(256) void conv2_stats_mfma(const unsigned short* __restrict__ h1,
    const unsigned short* __restrict__ w2t, const float* __restrict__ b2,
    float* __restrict__ part, int N)
{
    int t = threadIdx.x, wv = t >> 6, lane = t & 63;
    int li = lane & 15, grp = lane >> 4;
    short8v af[5][2];
#pragma unroll
    for (int kk = 0; kk < 5; ++kk)
#pragma unroll
        for (int mf = 0; mf < 2; ++mf)
            af[kk][mf] = *(const short8v*)(w2t + ((kk * 32 + mf * 16 + li) * 32 + grp * 8));
    float bc[2][4];
#pragma unroll
    for (int mf = 0; mf < 2; ++mf)
#pragma unroll
        for (int r = 0; r < 4; ++r) bc[mf][r] = b2[mf * 16 + grp * 4 + r];
    float sum[2][4] = {}, sq[2][4] = {};
    for (int n = blockIdx.x * 4 + wv; n < N; n += gridDim.x * 4) {
        const unsigned short* hb = h1 + (size_t)n * 2048;
#pragma unroll
        for (int lt = 0; lt < 4; ++lt) {
            float4v acc0 = {0.f, 0.f, 0.f, 0.f}, acc1 = {0.f, 0.f, 0.f, 0.f};
#pragma unroll
            for (int kk = 0; kk < 5; ++kk) {
                int row = lt * 16 + li + kk; row = row > 63 ? 63 : row;
                short8v bf = *(const short8v*)(hb + row * 32 + grp * 8);
                acc0 = __builtin_amdgcn_mfma_f32_16x16x32_bf16(af[kk][0], bf, acc0, 0, 0, 0);
                acc1 = __builtin_amdgcn_mfma_f32_16x16x32_bf16(af[kk][1], bf, acc1, 0, 0, 0);
            }
            if (lt * 16 + li < L2C) {
#pragma unroll
                for (int r = 0; r < 4; ++r) {
                    float y0 = acc0[r] + bc[0][r]; sum[0][r] += y0; sq[0][r] = fmaf(y0, y0, sq[0][r]);
                    float y1 = acc1[r] + bc[1][r]; sum[1][r] += y1; sq[1][r] = fmaf(y1, y1, sq[1][r]);
                }
            }
        }
    }
    __shared__ float redS[4][32], redQ[4][32];
#pragma unroll
    for (int mf = 0; mf < 2; ++mf)
#pragma unroll
        for (int r = 0; r < 4; ++r) {
            float s = sum[mf][r], q = sq[mf][r];
#pragma unroll
            for (int m = 1; m < 16; m <<= 1) { s += __shfl_xor(s, m); q += __shfl_xor(q, m); }
            if (li == 0) { redS[wv][mf * 16 + grp * 4 + r] = s; redQ[wv][mf * 16 + grp * 4 + r] = q; }
        }
    __syncthreads();
    if (t < 32) part[blockIdx.x * 64 + t] = redS[0][t] + redS[1][t] + redS[2][t] + redS[3][t];
    else if (t < 64) part[blockIdx.x * 64 + t] = redQ[0][t - 32] + redQ[1][t - 32] + redQ[2][t - 32] + redQ[3][t - 32];
}

// ---------------- conv2 apply via MFMA + BN + relu + pool -> z bf16 [n][352] ----------------
__global__ __launch_bounds__(256) void conv2_apply_mfma(const unsigned short* __restrict__ h1,
    const unsigned short* __restrict__ w2t, const float* __restrict__ b2,
    const float* __restrict__ mean, const float* __restrict__ istd,
    const float* __restrict__ g2, const float* __restrict__ be2,
    unsigned short* __restrict__ z, int N)
{
    __shared__ float yt[4][32][66];
    __shared__ float sc2[32], sh2[32], bcv[32];
    int t = threadIdx.x, wv = t >> 6, lane = t & 63;
    int li = lane & 15, grp = lane >> 4;
    if (t < 32) { float s = istd[t] * g2[t]; sc2[t] = s; sh2[t] = be2[t] - mean[t] * s; bcv[t] = b2[t]; }
    short8v af[5][2];
#pragma unroll
    for (int kk = 0; kk < 5; ++kk)
#pragma unroll
        for (int mf = 0; mf < 2; ++mf)
            af[kk][mf] = *(const short8v*)(w2t + ((kk * 32 + mf * 16 + li) * 32 + grp * 8));
    __syncthreads();
    for (int n = blockIdx.x * 4 + wv; n < N; n += gridDim.x * 4) {
        const unsigned short* hb = h1 + (size_t)n * 2048;
#pragma unroll
        for (int lt = 0; lt < 4; ++lt) {
            float4v acc0 = {0.f, 0.f, 0.f, 0.f}, acc1 = {0.f, 0.f, 0.f, 0.f};
#pragma unroll
            for (int kk = 0; kk < 5; ++kk) {
                int row = lt * 16 + li + kk; row = row > 63 ? 63 : row;
                short8v bf = *(const short8v*)(hb + row * 32 + grp * 8);
                acc0 = __builtin_amdgcn_mfma_f32_16x16x32_bf16(af[kk][0], bf, acc0, 0, 0, 0);
                acc1 = __builtin_amdgcn_mfma_f32_16x16x32_bf16(af[kk][1], bf, acc1, 0, 0, 0);
            }
#pragma unroll
            for (int r = 0; r < 4; ++r) {
                yt[wv][grp * 4 + r][lt * 16 + li] = acc0[r];
                yt[wv][16 + grp * 4 + r][lt * 16 + li] = acc1[r];
            }
        }
        unsigned short* zr = z + (size_t)n * VEC;
        for (int s = lane; s < VEC; s += 64) {
            int c = s / 11, lo = s % 11;
            float m = yt[wv][c][lo * 5];
#pragma unroll
            for (int d = 1; d < 5; ++d) m = fmaxf(m, yt[wv][c][lo * 5 + d]);
            float y = fmaf(sc2[c], m + bcv[c], sh2[c]);
            zr[s] = f2bf(fmaxf(y, 0.f));
        }
    }
}

// ---------------- support means ----------------
__global__ void sup_means(const unsigned short* __restrict__ z, float* __restrict__ misc)
{
    int v = blockIdx.x * 64 + threadIdx.x;
    if (v >= VEC) return;
    float s0 = 0.f, s1 = 0.f;
    for (int k = 0; k < 10; ++k) {
        s0 += bf2f(z[(size_t)k * VEC + v]);
        s1 += bf2f(z[(size_t)(10 + k) * VEC + v]);
    }
    misc[128 + v] = s0 * 0.1f;
    misc[480 + v] = s1 * 0.1f;
}

// ---------------- support-path gate GEMVs (fp32) ----------------
__global__ __launch_bounds__(128) void gates_gemv(int mode,
    const float* __restrict__ wihf, const float* __restrict__ whhf,
    const float* __restrict__ bihf, const float* __restrict__ bhhf,
    const float* __restrict__ wihr, const float* __restrict__ bihr,
    const float* __restrict__ bhhr, float* __restrict__ misc)
{
    __shared__ float s0[VEC], s1[VEC], h1f[VEC], h2f[VEC];
    int t = threadIdx.x;
    for (int i = t; i < VEC; i += 128) {
        s0[i] = misc[128 + i]; s1[i] = misc[480 + i];
        h1f[i] = misc[832 + i]; h2f[i] = misc[1536 + i];
    }
    __syncthreads();
    int j = blockIdx.x * 128 + t;
    if (j >= GATES) return;
    if (mode == 0) {
        float a = bihf[j] + bhhf[j];
        const float* w = wihf + (size_t)j * VEC;
        for (int k = 0; k < VEC; k += 4)
            a += w[k] * s0[k] + w[k + 1] * s0[k + 1] + w[k + 2] * s0[k + 2] + w[k + 3] * s0[k + 3];
        misc[2240 + j] = a;
    } else if (mode == 1) {
        float a = bihf[j] + bhhf[j];
        const float* w = wihf + (size_t)j * VEC;
        const float* wh = whhf + (size_t)j * VEC;
        for (int k = 0; k < VEC; k += 4) {
            a += w[k] * s1[k] + w[k + 1] * s1[k + 1] + w[k + 2] * s1[k + 2] + w[k + 3] * s1[k + 3];
            a += wh[k] * h1f[k] + wh[k + 1] * h1f[k + 1] + wh[k + 2] * h1f[k + 2] + wh[k + 3] * h1f[k + 3];
        }
        misc[3648 + j] = a;
    } else {
        float a = bihf[j] + bhhf[j];
        const float* wh = whhf + (size_t)j * VEC;
        for (int k = 0; k < VEC; k += 4)
            a += wh[k] * h2f[k] + wh[k + 1] * h2f[k + 1] + wh[k + 2] * h2f[k + 2] + wh[k + 3] * h2f[k + 3];
        misc[5056 + j] = a;
        float br = bihr[j] + bhhr[j];
        const float* wr = wihr + (size_t)j * VEC;
        float p1 = br, p0 = br;
        for (int k = 0; k < VEC; k += 4) {
            p1 += wr[k] * s1[k] + wr[k + 1] * s1[k + 1] + wr[k + 2] * s1[k + 2] + wr[k + 3] * s1[k + 3];
            p0 += wr[k] * s0[k] + wr[k + 1] * s0[k + 1] + wr[k + 2] * s0[k + 2] + wr[k + 3] * s0[k + 3];
        }
        misc[6464 + j] = p1;
        misc[7872 + j] = p0;
    }
}

__global__ void cell_small(const float* __restrict__ g, const float* __restrict__ cp,
    float* __restrict__ ho, float* __restrict__ co)
{
    int h = blockIdx.x * 64 + threadIdx.x;
    if (h >= HID) return;
    float iv = sigf(g[h]), fv = sigf(g[HID + h]);
    float gv = tanhf(g[2 * HID + h]), ov = sigf(g[3 * HID + h]);
    float c = iv * gv + (cp ? fv * cp[h] : 0.f);
    ho[h] = ov * tanhf(c);
    co[h] = c;
}

// ---------------- big LSTM step: bf16 MFMA GEMM + fused cell ----------------
__global__ __launch_bounds__(256) void lstm_mfma(
    const unsigned short* __restrict__ Xb, const unsigned short* __restrict__ Wb,
    const float* __restrict__ add1, const float* __restrict__ add2,
    const float* __restrict__ cprev, int cmode,
    float* __restrict__ hf, unsigned short* __restrict__ hbf, float* __restrict__ cf, int Q)
{
    int t = threadIdx.x, wv = t >> 6, lane = t & 63;
    int li = lane & 15, grp = lane >> 4;
    int q0 = blockIdx.x * 256 + wv * 64;
    int h0 = blockIdx.y * 16;
    int h = h0 + li;
    const unsigned short* xp[4];
#pragma unroll
    for (int mf = 0; mf < 4; ++mf) {
        int qr = q0 + mf * 16 + li;
        if (qr > Q - 1) qr = Q - 1;
        xp[mf] = Xb + (size_t)qr * VEC + grp * 8;
    }
    const unsigned short* wbase = Wb + (size_t)(h0 + li) * VEC + grp * 8;
    float4v acc[4][4];
#pragma unroll
    for (int gi = 0; gi < 4; ++gi)
#pragma unroll
        for (int mf = 0; mf < 4; ++mf) acc[gi][mf] = (float4v){0.f, 0.f, 0.f, 0.f};
#pragma unroll 2
    for (int ks = 0; ks < 11; ++ks) {
        int ko = ks * 32;
        short8v a0 = *(const short8v*)(xp[0] + ko);
        short8v a1 = *(const short8v*)(xp[1] + ko);
        short8v a2 = *(const short8v*)(xp[2] + ko);
        short8v a3 = *(const short8v*)(xp[3] + ko);
        short8v b0 = *(const short8v*)(wbase + ko);
        short8v b1 = *(const short8v*)(wbase + (size_t)HID * VEC + ko);
        short8v b2 = *(const short8v*)(wbase + (size_t)2 * HID * VEC + ko);
        short8v b3 = *(const short8v*)(wbase + (size_t)3 * HID * VEC + ko);
        acc[0][0] = __builtin_amdgcn_mfma_f32_16x16x32_bf16(a0, b0, acc[0][0], 0, 0, 0);
        acc[0][1] = __builtin_amdgcn_mfma_f32_16x16x32_bf16(a1, b0, acc[0][1], 0, 0, 0);
        acc[0][2] = __builtin_amdgcn_mfma_f32_16x16x32_bf16(a2, b0, acc[0][2], 0, 0, 0);
        acc[0][3] = __builtin_amdgcn_mfma_f32_16x16x32_bf16(a3, b0, acc[0][3], 0, 0, 0);
        acc[1][0] = __builtin_amdgcn_mfma_f32_16x16x32_bf16(a0, b1, acc[1][0], 0, 0, 0);
        acc[1][1] = __builtin_amdgcn_mfma_f32_16x16x32_bf16(a1, b1, acc[1][1], 0, 0, 0);
        acc[1][2] = __builtin_amdgcn_mfma_f32_16x16x32_bf16(a2, b1, acc[1][2], 0, 0, 0);
        acc[1][3] = __builtin_amdgcn_mfma_f32_16x16x32_bf16(a3, b1, acc[1][3], 0, 0, 0);
        acc[2][0] = __builtin_amdgcn_mfma_f32_16x16x32_bf16(a0, b2, acc[2][0], 0, 0, 0);
        acc[2][1] = __builtin_amdgcn_mfma_f32_16x16x32_bf16(a1, b2, acc[2][1], 0, 0, 0);
        acc[2][2] = __builtin_amdgcn_mfma_f32_16x16x32_bf16(a2, b2, acc[2][2], 0, 0, 0);
        acc[2][3] = __builtin_amdgcn_mfma_f32_16x16x32_bf16(a3, b2, acc[2][3], 0, 0, 0);
        acc[3][0] = __builtin_amdgcn_mfma_f32_16x16x32_bf16(a0, b3, acc[3][0], 0, 0, 0);
        acc[3][1] = __builtin_amdgcn_mfma_f32_16x16x32_bf16(a1, b3, acc[3][1], 0, 0, 0);
        acc[3][2] = __builtin_amdgcn_mfma_f32_16x16x32_bf16(a2, b3, acc[3][2], 0, 0, 0);
        acc[3][3] = __builtin_amdgcn_mfma_f32_16x16x32_bf16(a3, b3, acc[3][3], 0, 0, 0);
    }
    float ai = add1[h] + (add2 ? add2[h] : 0.f);
    float afv = add1[HID + h] + (add2 ? add2[HID + h] : 0.f);
    float ag = add1[2 * HID + h] + (add2 ? add2[2 * HID + h] : 0.f);
    float ao = add1[3 * HID + h] + (add2 ? add2[3 * HID + h] : 0.f);
    float cc1 = (cmode == 1) ? cprev[h] : 0.f;
#pragma unroll
    for (int mf = 0; mf < 4; ++mf) {
#pragma unroll
        for (int r = 0; r < 4; ++r) {
            int q = q0 + mf * 16 + grp * 4 + r;
            if (q >= Q) continue;
            float iv = sigf(acc[0][mf][r] + ai);
            float fv = sigf(acc[1][mf][r] + afv);
            float gv = tanhf(acc[2][mf][r] + ag);
            float ov = sigf(acc[3][mf][r] + ao);
            float cp = (cmode == 2) ? cprev[(size_t)q * HID + h] : cc1;
            float cn = fv * cp + iv * gv;
            float hn = ov * tanhf(cn);
            hf[(size_t)q * HID + h] = hn;
            if (hbf) hbf[(size_t)q * HID + h] = f2bf(hn);
            if (cf) cf[(size_t)q * HID + h] = cn;
        }
    }
}

// ---------------- cosine sims + softmax; one wave per query ----------------
__global__ __launch_bounds__(256) void final_sims(
    const float* __restrict__ h3f, const float* __restrict__ hb1,
    const float* __restrict__ hb2, const float* __restrict__ hb3,
    const float* __restrict__ misc, float* __restrict__ out, int Q)
{
    int t = threadIdx.x;
    int wave = t >> 6, lane = t & 63;
    int q = blockIdx.x * 4 + wave;
    if (q >= Q) return;
    const float* a3 = h3f + (size_t)q * HID;
    const float* b1 = hb1 + (size_t)q * HID;
    const float* b2 = hb2 + (size_t)q * HID;
    const float* b3 = hb3 + (size_t)q * HID;
    const float* h1c = misc + 832;
    const float* h2c = misc + 1536;
    float sA = 0, sB = 0, s3 = 0, s4 = 0, s5 = 0, s6 = 0, s7 = 0, s8 = 0, s9 = 0, s10 = 0;
    for (int hh = lane; hh < HID; hh += 64) {
        float a = a3[hh], b = b1[hh], v2 = b2[hh], v3 = b3[hh];
        float u1 = h1c[hh], u2 = h2c[hh];
        sA += u1 * a;  sB += u2 * a;
        s3 += a * a;   s4 += b * b;
        s5 += v3 * b;  s6 += v2 * b;
        s7 += v3 * v3; s8 += v2 * v2;
        s9 += u1 * u1; s10 += u2 * u2;
    }
#pragma unroll
    for (int off = 32; off > 0; off >>= 1) {
        sA += __shfl_xor(sA, off);  sB += __shfl_xor(sB, off);
        s3 += __shfl_xor(s3, off);  s4 += __shfl_xor(s4, off);
        s5 += __shfl_xor(s5, off);  s6 += __shfl_xor(s6, off);
        s7 += __shfl_xor(s7, off);  s8 += __shfl_xor(s8, off);
        s9 += __shfl_xor(s9, off);  s10 += __shfl_xor(s10, off);
    }
    if (lane == 0) {
        float nq  = fmaxf(sqrtf(s3 + s4), 1e-8f);
        float ns0 = fmaxf(sqrtf(s9 + s7), 1e-8f);
        float ns1 = fmaxf(sqrtf(s10 + s8), 1e-8f);
        float sim0 = (sA + s5) / (ns0 * nq);
        float sim1 = (sB + s6) / (ns1 * nq);
        float mx = fmaxf(sim0, sim1);
        float e0 = __expf(sim0 - mx), e1 = __expf(sim1 - mx);
        float inv = 1.f / (e0 + e1);
        out[(size_t)q * 2 + 0] = e0 * inv;
        out[(size_t)q * 2 + 1] = e1 * inv;
    }
}

extern "C" void kernel_launch(void* const* d_in, const int* in_sizes, int n_in,
                              void* d_out, int out_size, void* d_ws, size_t ws_size,
                              hipStream_t stream)
{
    const float* x    = (const float*)d_in[0];
    const float* c1w  = (const float*)d_in[1];
    const float* c1b  = (const float*)d_in[2];
    const float* bn1g = (const float*)d_in[3];
    const float* bn1b = (const float*)d_in[4];
    const float* c2w  = (const float*)d_in[5];
    const float* c2b  = (const float*)d_in[6];
    const float* bn2g = (const float*)d_in[7];
    const float* bn2b = (const float*)d_in[8];
    const float* wihf = (const float*)d_in[9];
    const float* whhf = (const float*)d_in[10];
    const float* bihf = (const float*)d_in[11];
    const float* bhhf = (const float*)d_in[12];
    const float* wihr = (const float*)d_in[13];
    const float* whhr = (const float*)d_in[14];
    const float* bihr = (const float*)d_in[15];
    const float* bhhr = (const float*)d_in[16];

    int N = in_sizes[0] / LIN;
    int Q = N - NSUP;

    char* ws = (char*)d_ws;
    float* part1 = (float*)(ws + 0);                       // 2048*64 f32 = 512KB
    float* part2 = (float*)(ws + 524288);                  // 2048*64 f32 = 512KB
    float* misc  = (float*)(ws + 1048576);                 // ~9.3K f32
    unsigned short* w2t    = (unsigned short*)(ws + 1114112);      // 5120 bf16
    unsigned short* wihf_b = (unsigned short*)(ws + 2097152);
    unsigned short* wihr_b = (unsigned short*)(ws + 3145728);
    unsigned short* whhr_b = (unsigned short*)(ws + 4194304);
    unsigned short* z      = (unsigned short*)(ws + 5242880);      // N*352 bf16
    unsigned short* h1     = (unsigned short*)(ws + 17825792);     // N*64*32 bf16 (dead after conv2)
    const size_t S4 = (size_t)Q * HID * sizeof(float);
    float* h3f = (float*)(ws + 17825792);                  // over h1 (dead)
    float* hb1 = (float*)(ws + 17825792 + S4);
    unsigned short* hb1b = (unsigned short*)(ws + 17825792 + 2 * S4);
    float* cb1 = (float*)(ws + 17825792 + 2 * S4 + S4 / 2);
    float* hb2 = (float*)(ws + 17825792 + 3 * S4 + S4 / 2);
    unsigned short* hb2b = (unsigned short*)(ws + 17825792 + 4 * S4 + S4 / 2);
    float* cb2 = (float*)(ws + 17825792 + 5 * S4);
    float* hb3 = (float*)(ws + 17825792 + 2 * S4);         // over hb1b+cb1 (dead after GEMM3)

    // 1. cast weights
    {
        int tot = 3 * GATES * VEC + 5120;
        cast_weights<<<(tot + 255) / 256, 256, 0, stream>>>(wihf, wihr, whhr, c2w,
                                                            wihf_b, wihr_b, whhr_b, w2t);
    }
    // 2. conv1: stats + pooled raw
    conv1_pass1<<<NBLK, 256, 0, stream>>>(x, c1w, c1b, part1, h1, N);
    finalize_stats2<<<1, 512, 0, stream>>>(part1, misc + 0, misc + 32, (float)((long long)N * L1C));
    // 3. conv1 BN+relu in place
    {
        long long total = (long long)N * 236;
        conv1_pass2<<<(unsigned)((total + 255) / 256), 256, 0, stream>>>(h1, misc + 0, misc + 32, bn1g, bn1b, total);
    }
    // 4. conv2 stats
    conv2_stats_mfma<<<NBLK, 256, 0, stream>>>(h1, w2t, c2b, part2, N);
    finalize_stats2<<<1, 512, 0, stream>>>(part2, misc + 64, misc + 96, (float)((long long)N * L2C));
    // 5. conv2 apply -> z
    conv2_apply_mfma<<<NBLK, 256, 0, stream>>>(h1, w2t, c2b, misc + 64, misc + 96, bn2g, bn2b, z, N);
    // 6. support path
    sup_means<<<6, 64, 0, stream>>>(z, misc);
    gates_gemv<<<11, 128, 0, stream>>>(0, wihf, whhf, bihf, bhhf, wihr, bihr, bhhr, misc);
    cell_small<<<6, 64, 0, stream>>>(misc + 2240, nullptr, misc + 832, misc + 1184);
    gates_gemv<<<11, 128, 0, stream>>>(1, wihf, whhf, bihf, bhhf, wihr, bihr, bhhr, misc);
    cell_small<<<6, 64, 0, stream>>>(misc + 3648, misc + 1184, misc + 1536, misc + 1888);
    gates_gemv<<<11, 128, 0, stream>>>(2, wihf, whhf, bihf, bhhf, wihr, bihr, bhhr, misc);
    // 7. big LSTM steps
    const unsigned short* zq = z + (size_t)NSUP * VEC;
    dim3 gg((Q + 255) / 256, 22);
    lstm_mfma<<<gg, 256, 0, stream>>>(zq, wihf_b, misc + 5056, nullptr, misc + 1888, 1, h3f, nullptr, nullptr, Q);
    lstm_mfma<<<gg, 256, 0, stream>>>(zq, wihr_b, bihr, bhhr, nullptr, 0, hb1, hb1b, cb1, Q);
    lstm_mfma<<<gg, 256, 0, stream>>>(hb1b, whhr_b, misc + 6464, nullptr, cb1, 2, hb2, hb2b, cb2, Q);
    lstm_mfma<<<gg, 256, 0, stream>>>(hb2b, whhr_b, misc + 7872, nullptr, cb2, 2, hb3, nullptr, nullptr, Q);
    // 8. sims + softmax
    final_sims<<<(Q + 3) / 4, 256, 0, stream>>>(h3f, hb1, hb2, hb3, misc, (float*)d_out, Q);
}